// Round 2
// baseline (263.126 us; speedup 1.0000x reference)
//
#include <hip/hip_runtime.h>
#include <hip/hip_bf16.h>

#define BB 8
#define NN 65536
#define CC 64
#define MM 64

typedef __attribute__((ext_vector_type(8))) short bf16x8;
typedef __attribute__((ext_vector_type(4))) float f32x4;
typedef unsigned int u32;
typedef unsigned short u16;

__device__ inline u32 pk_bf2(float a, float b) {
  __hip_bfloat162 h = __float22bfloat162_rn(make_float2(a, b));
  u32 r;
  __builtin_memcpy(&r, &h, 4);
  return r;
}

__device__ inline u16 sbf(float a) {
  __hip_bfloat16 h = __float2bfloat16(a);
  u16 r;
  __builtin_memcpy(&r, &h, 2);
  return r;
}

// t in REVOLUTIONS (= coord . freq). v_sin_f32/v_cos_f32 compute sin(2*pi*x);
// fract first keeps input in [0,1) (valid HW range), preserves value exactly.
__device__ inline void rsc(float t, float& sn, float& cs) {
  const float tf = __builtin_amdgcn_fractf(t);
  sn = __builtin_amdgcn_sinf(tf);
  cs = __builtin_amdgcn_cosf(tf);
}

// ============================ Pass 1: projection =============================
// partial[blk][m'][c] = sum_{n in chunk} A1[m'][n] * x[n][c]
// A1[m][n]=cos, A1[m+64][n]=sin. Double-buffered LDS, DISTANCE-2 register
// prefetch, one barrier per 64-point step, raw v_sin/v_cos.
#define CH1 64
#define STEPS1 16   // 1024 points per block, 64 per step

__global__ __launch_bounds__(256) void proj_mfma(
    const float* __restrict__ inputs,   // [B][N][C]
    const float* __restrict__ coords,   // [B][N][2]
    const float* __restrict__ freqs,    // [M][2]
    float* __restrict__ partial)        // [BB*CH1][128][64] fp32
{
  __shared__ __align__(16) u16 As[2][128 * 64];  // basis [m'][k] swizzled
  __shared__ __align__(16) u16 Xs[2][64 * 64];   // x^T   [c ][k] swizzled

  const int tid   = threadIdx.x;
  const int b     = blockIdx.x >> 6;
  const int nbase = (blockIdx.x & 63) * 1024;
  const int lane  = tid & 63;
  const int wave  = tid >> 6;
  const int l15   = lane & 15;
  const int quad  = lane >> 4;

  // basis staging role: point-pair q (k=2q,2q+1), mode octet mg (8 modes)
  const int q  = tid & 31;
  const int mg = tid >> 5;       // 0..7
  // X staging role
  const int np = tid & 15;
  const int cq = tid >> 4;       // 0..15

  float fqx[8], fqy[8];
#pragma unroll
  for (int mm = 0; mm < 8; ++mm) {
    fqx[mm] = freqs[2 * (mg * 8 + mm)];
    fqy[mm] = freqs[2 * (mg * 8 + mm) + 1];
  }

  const float4* c4 = (const float4*)coords;
  const float4* x4 = (const float4*)inputs;
  const size_t cbase = ((size_t)b * NN + nbase) >> 1;  // float4 units (2 pts each)
  const size_t xbase = ((size_t)b * NN + nbase) * 16;  // float4 units

  float4 cs_[2];       // coord prefetch slots (1 float4 = 2 points)
  float4 xs_[2][4];    // X prefetch slots (4 float4)

  auto do_load = [&](int s, int slot) {
    cs_[slot] = c4[cbase + (size_t)s * 32 + q];
#pragma unroll
    for (int half = 0; half < 2; ++half) {
      const int n = s * 64 + half * 32 + 2 * np;
      xs_[slot][half * 2 + 0] = x4[xbase + (size_t)n * 16 + cq];
      xs_[slot][half * 2 + 1] = x4[xbase + (size_t)(n + 1) * 16 + cq];
    }
  };

  auto do_stage = [&](int slot, int buf) {
    const float4 cp = cs_[slot];
    const int k8 = q >> 2;
    const int ko = (2 * q) & 7;
#pragma unroll
    for (int mm = 0; mm < 8; ++mm) {
      const int rc = mg * 8 + mm;
      const int rs = rc + 64;
      float s0, c0, s1, c1;
      rsc(fmaf(cp.x, fqx[mm], cp.y * fqy[mm]), s0, c0);
      rsc(fmaf(cp.z, fqx[mm], cp.w * fqy[mm]), s1, c1);
      *(u32*)&As[buf][rc * 64 + ((k8 + rc) & 7) * 8 + ko] = pk_bf2(c0, c1);
      *(u32*)&As[buf][rs * 64 + ((k8 + rs) & 7) * 8 + ko] = pk_bf2(s0, s1);
    }
#pragma unroll
    for (int half = 0; half < 2; ++half) {
      const int k = half * 32 + 2 * np;
      const int k8x = k >> 3, kox = k & 7;
      const float* p0 = (const float*)&xs_[slot][half * 2 + 0];
      const float* p1 = (const float*)&xs_[slot][half * 2 + 1];
#pragma unroll
      for (int j = 0; j < 4; ++j) {
        const int c = cq * 4 + j;
        *(u32*)&Xs[buf][c * 64 + ((k8x + c) & 7) * 8 + kox] = pk_bf2(p0[j], p1[j]);
      }
    }
  };

  f32x4 acc[2][4];
#pragma unroll
  for (int rt = 0; rt < 2; ++rt)
#pragma unroll
    for (int ct = 0; ct < 4; ++ct) acc[rt][ct] = (f32x4){0.f, 0.f, 0.f, 0.f};

  auto do_mfma = [&](int buf) {
#pragma unroll
    for (int kk = 0; kk < 2; ++kk) {
      const int k8q = kk * 4 + quad;
      const int r0 = wave * 32 + l15;
      const int r1 = r0 + 16;
      const bf16x8 a0 = *(const bf16x8*)&As[buf][r0 * 64 + ((k8q + r0) & 7) * 8];
      const bf16x8 a1 = *(const bf16x8*)&As[buf][r1 * 64 + ((k8q + r1) & 7) * 8];
      bf16x8 bfr[4];
#pragma unroll
      for (int ct = 0; ct < 4; ++ct) {
        const int c = ct * 16 + l15;
        bfr[ct] = *(const bf16x8*)&Xs[buf][c * 64 + ((k8q + c) & 7) * 8];
      }
#pragma unroll
      for (int ct = 0; ct < 4; ++ct) {
        acc[0][ct] = __builtin_amdgcn_mfma_f32_16x16x32_bf16(a0, bfr[ct], acc[0][ct], 0, 0, 0);
        acc[1][ct] = __builtin_amdgcn_mfma_f32_16x16x32_bf16(a1, bfr[ct], acc[1][ct], 0, 0, 0);
      }
    }
  };

  do_load(0, 0);
  do_load(1, 1);
  do_stage(0, 0);
  __syncthreads();

#pragma unroll
  for (int s = 0; s < STEPS1; ++s) {
    const int cur = s & 1;
    if (s + 2 < STEPS1) do_load(s + 2, cur);   // slot cur was consumed by stage(s)
    do_mfma(cur);
    if (s + 1 < STEPS1) do_stage(1 - cur, 1 - cur);
    __syncthreads();                            // one barrier per step
  }

  // ---- flush: coalesced stores of this block's partial tile ----
  float* pb = partial + (size_t)blockIdx.x * (128 * 64);
#pragma unroll
  for (int rt = 0; rt < 2; ++rt)
#pragma unroll
    for (int ct = 0; ct < 4; ++ct)
#pragma unroll
      for (int r = 0; r < 4; ++r) {
        const int mrow = wave * 32 + rt * 16 + quad * 4 + r;
        const int c = ct * 16 + l15;
        pb[mrow * 64 + c] = acc[rt][ct][r];
      }
}

// ============================ Pass 1.5: reduce + mix ========================
__global__ __launch_bounds__(256) void mix_kernel(
    const float* __restrict__ partial,  // [BB*CH1][128][64]
    const float* __restrict__ wre, const float* __restrict__ wim,
    u16* __restrict__ w2t)              // [BB][64][128]
{
  const int idx = blockIdx.x * 256 + threadIdx.x;  // 32768 total
  const int b = idx >> 12;
  const int m = (idx >> 6) & 63;
  const int c = idx & 63;
  const float* pb = partial + (size_t)b * CH1 * 8192;
  float gre = 0.f, gim = 0.f;
#pragma unroll 8
  for (int k = 0; k < CH1; ++k) {
    gre += pb[(size_t)k * 8192 + m * 64 + c];
    gim += pb[(size_t)k * 8192 + (64 + m) * 64 + c];
  }
  const float invN = 1.0f / (float)NN;
  const float wr = wre[m * 64 + c], wi = wim[m * 64 + c];
  u16* wb_ = w2t + (size_t)b * 64 * 128;
  wb_[c * 128 + m]      = sbf((gre * wr + gim * wi) * invN);
  wb_[c * 128 + 64 + m] = sbf((gim * wr - gre * wi) * invN);
}

// ============================ Pass 2: reconstruction ========================
// out[n][c] = sum_{m'} P[n][m'] * W2[m'][c]. Double-buffered Ps, distance-2
// coord prefetch, raw sincos, one barrier per 128-point tile.
// OPERAND-SWAPPED MFMA: mfma(W2-frag, P-frag) computes D[c][n] with
// row(=quad*4+reg)=c, col(=lane&15)=n  ->  each thread's 4 acc regs are 4
// CONSECUTIVE c at one n  ->  one aligned float4 store (8 dwordx4/tile
// instead of 32 scalar dwords). A/B fragments for 16x16x32 have identical
// lane->(index,k) layouts, so the existing wb / a0 / a1 register contents
// are reused unchanged — only the argument order and the store indexing
// change (provably equivalent to the harness-verified original).
#define TILES2 8   // 1024 points per block

__global__ __launch_bounds__(256) void recon_mfma(
    const float* __restrict__ coords,   // [B][N][2]
    const u16* __restrict__ w2t,        // [B][64][128] bf16
    const float* __restrict__ freqs,    // [M][2]
    float* __restrict__ out)            // [B][N][C] fp32
{
  __shared__ __align__(16) u16 Ps[2][128 * 128];  // 2 x 32 KB
  __shared__ float sfx[64], sfy[64];

  const int tid   = threadIdx.x;
  const int b     = blockIdx.x >> 6;
  const int nbase = (blockIdx.x & 63) * 1024;
  const int lane  = tid & 63;
  const int wave  = tid >> 6;
  const int l15   = lane & 15;
  const int quad  = lane >> 4;

  if (tid < 64) { sfx[tid] = freqs[2 * tid]; sfy[tid] = freqs[2 * tid + 1]; }

  const int p  = tid & 127;        // point within tile
  const int mg = (tid >> 7) * 32;  // 32-mode group
  const float2* c2 = (const float2*)coords;
  const size_t cb = (size_t)b * NN + nbase;

  // coord prefetch, distance 2
  float2 cpre[2];
  cpre[0] = c2[cb + p];
  cpre[1] = c2[cb + 128 + p];

  // preload all 16 W2 fragments from global (used as the A-operand now;
  // register layout is identical to the old B-operand use)
  bf16x8 wb[4][4];
#pragma unroll
  for (int kc = 0; kc < 4; ++kc)
#pragma unroll
    for (int ct = 0; ct < 4; ++ct)
      wb[kc][ct] = *(const bf16x8*)&w2t[((size_t)b * 64 + ct * 16 + l15) * 128 +
                                        kc * 32 + quad * 8];
  __syncthreads();  // sfx/sfy visible

  auto stage_tile = [&](int buf, float2 cc) {
#pragma unroll
    for (int g = 0; g < 4; ++g) {
      u32 cpk[4], spk[4];
#pragma unroll
      for (int jj = 0; jj < 4; ++jj) {
        const int m = mg + g * 8 + jj * 2;
        float s0, c0, s1, c1;
        rsc(fmaf(cc.x, sfx[m], cc.y * sfy[m]), s0, c0);
        rsc(fmaf(cc.x, sfx[m + 1], cc.y * sfy[m + 1]), s1, c1);
        cpk[jj] = pk_bf2(c0, c1);
        spk[jj] = pk_bf2(s0, s1);
      }
      const int k8c = (mg >> 3) + g;   // cos chunks 0..7
      const int k8s = k8c + 8;         // sin chunks 8..15
      *(uint4*)&Ps[buf][p * 128 + ((k8c + p) & 15) * 8] =
          make_uint4(cpk[0], cpk[1], cpk[2], cpk[3]);
      *(uint4*)&Ps[buf][p * 128 + ((k8s + p) & 15) * 8] =
          make_uint4(spk[0], spk[1], spk[2], spk[3]);
    }
  };

  stage_tile(0, cpre[0]);
  __syncthreads();

#pragma unroll
  for (int t = 0; t < TILES2; ++t) {
    const int cur = t & 1;
    if (t + 2 < TILES2) cpre[cur] = c2[cb + (size_t)(t + 2) * 128 + p];

    f32x4 acc[2][4];
#pragma unroll
    for (int rt = 0; rt < 2; ++rt)
#pragma unroll
      for (int ct = 0; ct < 4; ++ct) acc[rt][ct] = (f32x4){0.f, 0.f, 0.f, 0.f};

#pragma unroll
    for (int kc = 0; kc < 4; ++kc) {
      const int k8q = kc * 4 + quad;
      const int r0 = wave * 32 + l15;
      const int r1 = r0 + 16;
      const bf16x8 a0 = *(const bf16x8*)&Ps[cur][r0 * 128 + ((k8q + r0) & 15) * 8];
      const bf16x8 a1 = *(const bf16x8*)&Ps[cur][r1 * 128 + ((k8q + r1) & 15) * 8];
#pragma unroll
      for (int ct = 0; ct < 4; ++ct) {
        // swapped operands: D[c][n] instead of D[n][c]
        acc[0][ct] = __builtin_amdgcn_mfma_f32_16x16x32_bf16(wb[kc][ct], a0, acc[0][ct], 0, 0, 0);
        acc[1][ct] = __builtin_amdgcn_mfma_f32_16x16x32_bf16(wb[kc][ct], a1, acc[1][ct], 0, 0, 0);
      }
    }

    if (t + 1 < TILES2) stage_tile(1 - cur, cpre[1 - cur]);

    float* ob = out + (cb + (size_t)t * 128) * 64;
#pragma unroll
    for (int rt = 0; rt < 2; ++rt)
#pragma unroll
      for (int ct = 0; ct < 4; ++ct) {
        // thread owns n = wave*32 + rt*16 + l15 (col index of D),
        // c = ct*16 + quad*4 + {0..3} (row index of D, the 4 acc regs)
        const int n = wave * 32 + rt * 16 + l15;
        *(f32x4*)&ob[(size_t)n * 64 + ct * 16 + quad * 4] = acc[rt][ct];
      }

    __syncthreads();  // one barrier per tile
  }
}

extern "C" void kernel_launch(void* const* d_in, const int* in_sizes, int n_in,
                              void* d_out, int out_size, void* d_ws, size_t ws_size,
                              hipStream_t stream) {
  const float* inputs = (const float*)d_in[0];
  const float* coords = (const float*)d_in[1];
  const float* wre    = (const float*)d_in[2];
  const float* wim    = (const float*)d_in[3];
  const float* freqs  = (const float*)d_in[4];
  float* out = (float*)d_out;

  float* partial = (float*)d_ws;  // [512][128][64] fp32 = 16 MB
  u16*   w2t     = (u16*)((char*)d_ws + (size_t)BB * CH1 * 128 * 64 * 4);

  proj_mfma<<<dim3(BB * CH1), dim3(256), 0, stream>>>(inputs, coords, freqs, partial);
  mix_kernel<<<dim3(128), dim3(256), 0, stream>>>(partial, wre, wim, w2t);
  recon_mfma<<<dim3(BB * CH1), dim3(256), 0, stream>>>(coords, w2t, freqs, out);
}